// Round 12
// baseline (68.938 us; speedup 1.0000x reference)
//
#include <hip/hip_runtime.h>

#define NUM_FRAMES 1000
#define NUM_CAM    8
#define CROW       12   // cam channel row: {cx,cy,a2,a3, a4,k1,k2,k3, k4,pad,pad,pad}

// ws layout (bytes): [0)      h8 ftab[1000]        16384
//                    [16384)  _Float16 o5[1000]  -> pad to 2048
//                    [18432)  float cam[288]       1152   (real end: 19584)
//                    [19584)  pad to 32768 (stays 0xAA; staged but never read)
#define WS_O5_OFF   16384
#define WS_CAM_OFF  18432
#define WS_REAL     19584
#define WS_PAD      32768   // 2048 int4 -> exactly 2 int4 per thread at 1024 threads

typedef _Float16 h8 __attribute__((ext_vector_type(8)));

struct __align__(4) F3 { float x, y, z; };

__device__ __forceinline__ float softplus_acc(float x) {
    return (x > 20.0f) ? x : log1pf(expf(x));
}

// fast CRF core: inputs clamped >=1e-6 (no denormals), so raw v_log_f32/v_exp_f32 are safe
__device__ __forceinline__ float crf_pow(float m, float k3) {
    return __builtin_amdgcn_exp2f(k3 * __builtin_amdgcn_logf(fmaxf(m, 1e-6f)));
}

// ---------------- setup: bake packed tables into d_ws once ----------------
__global__ void build_tables(const float* __restrict__ expo,
                             const float* __restrict__ cp,
                             const float* __restrict__ vigp,
                             const float* __restrict__ crf,
                             unsigned char* __restrict__ ws)
{
    h8*       ftab = (h8*)ws;
    _Float16* o5t  = (_Float16*)(ws + WS_O5_OFF);
    float*    camt = (float*)(ws + WS_CAM_OFF);

    int t = blockIdx.x * blockDim.x + threadIdx.x;
    if (t < NUM_FRAMES) {
        float e = expo[t];
        const float* c = cp + t * 8;
        h8 row;
        row[0] = (_Float16)expf(e + c[0]);
        row[1] = (_Float16)expf(e);
        row[2] = (_Float16)expf(e + c[1]);
        row[3] = (_Float16)c[2];
        row[4] = (_Float16)c[3];
        row[5] = (_Float16)c[4];
        row[6] = (_Float16)c[5];
        row[7] = (_Float16)c[6];
        ftab[t] = row;
        o5t[t]  = (_Float16)c[7];
    }
    if (t < NUM_CAM * 3) {
        const float* v = vigp + t * 5;
        const float* k = crf + t * 4;
        float* d = camt + t * CROW;
        d[0] = v[0]; d[1] = v[1]; d[2] = v[2]; d[3] = v[3];
        d[4] = v[4];
        d[5] = 0.3f + softplus_acc(k[0]);
        d[6] = 0.3f + softplus_acc(k[1]);
        d[7] = 0.1f + softplus_acc(k[2]);
        d[8] = k[3];
        d[9] = 0.f; d[10] = 0.f; d[11] = 0.f;
    }
}

// ---------------- per-pixel math ----------------
__device__ __forceinline__ void ppisp_px(
    float r, float g, float b, float px, float py,
    int cam, h8 fr, float o5, float invw, float invh,
    const float* __restrict__ s_cam,
    float* o)
{
    float er = (float)fr[0], eg = (float)fr[1], eb = (float)fr[2];
    float o0 = (float)fr[3], o1 = (float)fr[4], o2 = (float)fr[5];
    float o3 = (float)fr[6], o4 = (float)fr[7];

    float nx = px * invw - 0.5f;
    float ny = py * invh - 0.5f;

    float xin[3] = { r * er, g * eg, b * eb };
    float xv[3];
    float k1v[3], k2v[3], k3v[3], k4v[3];
#pragma unroll
    for (int ch = 0; ch < 3; ++ch) {
        const float* c = s_cam + (cam * 3 + ch) * CROW;
        float4 c0 = *(const float4*)(c);      // cx,cy,a2,a3
        float4 c1 = *(const float4*)(c + 4);  // a4,k1,k2,k3
        float  k4 = c[8];
        float dx = nx - c0.x;
        float dy = ny - c0.y;
        float r2 = __builtin_fmaf(dx, dx, dy * dy);
        float vg = __builtin_fmaf(__builtin_fmaf(__builtin_fmaf(c1.x, r2, c0.w), r2, c0.z), r2, 1.0f);
        xv[ch] = xin[ch] * vg;
        k1v[ch] = c1.y; k2v[ch] = c1.z; k3v[ch] = c1.w; k4v[ch] = k4;
    }

    float m[3];
    m[0] = __builtin_fmaf(o0, xv[1], __builtin_fmaf(o1, xv[2], xv[0]));
    m[1] = __builtin_fmaf(o2, xv[0], __builtin_fmaf(o3, xv[2], xv[1]));
    m[2] = __builtin_fmaf(o4, xv[0], __builtin_fmaf(o5, xv[1], xv[2]));

#pragma unroll
    for (int ch = 0; ch < 3; ++ch) {
        float xg  = crf_pow(m[ch], k3v[ch]);
        float den = __builtin_fmaf(k1v[ch] - 1.0f, xg, k2v[ch]);
        o[ch] = __builtin_fmaf(k1v[ch] * xg, __builtin_amdgcn_rcpf(den), k4v[ch]);
    }
}

// process one 4-px group given preloaded streaming inputs (generic path)
__device__ __forceinline__ void ppisp_group(
    int gi, float4 r0, float4 r1, float4 r2, float4 p0, float4 p1,
    int4 cm, int4 fm, float invw, float invh,
    const h8* __restrict__ s_frame8, const _Float16* __restrict__ s_o5h,
    const float* __restrict__ s_cam, float4* __restrict__ out4)
{
    h8 f0 = s_frame8[fm.x];
    h8 f1 = s_frame8[fm.y];
    h8 f2 = s_frame8[fm.z];
    h8 f3 = s_frame8[fm.w];
    float o5a = (float)s_o5h[fm.x];
    float o5b = (float)s_o5h[fm.y];
    float o5c = (float)s_o5h[fm.z];
    float o5d = (float)s_o5h[fm.w];

    float a[3], bb[3], c[3], d[3];
    ppisp_px(r0.x, r0.y, r0.z, p0.x, p0.y, cm.x, f0, o5a, invw, invh, s_cam, a);
    ppisp_px(r0.w, r1.x, r1.y, p0.z, p0.w, cm.y, f1, o5b, invw, invh, s_cam, bb);
    ppisp_px(r1.z, r1.w, r2.x, p1.x, p1.y, cm.z, f2, o5c, invw, invh, s_cam, c);
    ppisp_px(r2.y, r2.z, r2.w, p1.z, p1.w, cm.w, f3, o5d, invw, invh, s_cam, d);

    out4[gi * 3 + 0] = make_float4(a[0], a[1], a[2], bb[0]);
    out4[gi * 3 + 1] = make_float4(bb[1], bb[2], c[0], c[1]);
    out4[gi * 3 + 2] = make_float4(c[2], d[0], d[1], d[2]);
}

// ---- exact kernel: 1024 threads, 4 px/thread (i, i+1024, i+2048, i+3072);
//      stage loads oldest, all px loads before the barrier ----
__global__ __launch_bounds__(1024, 8)
void ppisp_px4(const float* __restrict__ rgb,
               const float* __restrict__ pc,
               const int*   __restrict__ cam_idx,
               const int*   __restrict__ frm_idx,
               const unsigned char* __restrict__ ws,
               const int*   __restrict__ resw_p,
               const int*   __restrict__ resh_p,
               float* __restrict__ out)
{
    __shared__ __align__(16) unsigned char s_tab[WS_PAD];

    int i0 = blockIdx.x * 4096 + threadIdx.x;
    int i1 = i0 + 1024;
    int i2 = i0 + 2048;
    int i3 = i0 + 3072;

    // 1) stage loads FIRST (oldest in vmcnt order)
    const int4* g = (const int4*)ws;
    int4 st0 = g[threadIdx.x];
    int4 st1 = g[threadIdx.x + 1024];

    // 2) all 4 pixels' streaming loads (younger) — latency overlaps barrier drain
    int frm0 = frm_idx[i0], frm1 = frm_idx[i1], frm2 = frm_idx[i2], frm3 = frm_idx[i3];
    int cam0 = cam_idx[i0], cam1 = cam_idx[i1], cam2 = cam_idx[i2], cam3 = cam_idx[i3];
    const F3* rgb3 = (const F3*)rgb;
    const float2* pc2 = (const float2*)pc;
    F3 v0 = rgb3[i0], v1 = rgb3[i1], v2 = rgb3[i2], v3 = rgb3[i3];
    float2 p0 = pc2[i0], p1 = pc2[i1], p2 = pc2[i2], p3 = pc2[i3];
    int rw = *resw_p;
    int rh = *resh_p;

    // 3) staging writes + barrier
    int4* s = (int4*)s_tab;
    s[threadIdx.x] = st0;
    s[threadIdx.x + 1024] = st1;
    __syncthreads();

    const h8*       s_frame8 = (const h8*)s_tab;
    const _Float16* s_o5h    = (const _Float16*)(s_tab + WS_O5_OFF);
    const float*    s_cam    = (const float*)(s_tab + WS_CAM_OFF);

    float invw = 1.0f / (float)rw;
    float invh = 1.0f / (float)rh;

    F3* out3 = (F3*)out;

    // 4) four independent gather+compute+store sections
    {
        h8 fr = s_frame8[frm0];
        float o5 = (float)s_o5h[frm0];
        float o[3];
        ppisp_px(v0.x, v0.y, v0.z, p0.x, p0.y, cam0, fr, o5, invw, invh, s_cam, o);
        F3 w; w.x = o[0]; w.y = o[1]; w.z = o[2];
        out3[i0] = w;
    }
    {
        h8 fr = s_frame8[frm1];
        float o5 = (float)s_o5h[frm1];
        float o[3];
        ppisp_px(v1.x, v1.y, v1.z, p1.x, p1.y, cam1, fr, o5, invw, invh, s_cam, o);
        F3 w; w.x = o[0]; w.y = o[1]; w.z = o[2];
        out3[i1] = w;
    }
    {
        h8 fr = s_frame8[frm2];
        float o5 = (float)s_o5h[frm2];
        float o[3];
        ppisp_px(v2.x, v2.y, v2.z, p2.x, p2.y, cam2, fr, o5, invw, invh, s_cam, o);
        F3 w; w.x = o[0]; w.y = o[1]; w.z = o[2];
        out3[i2] = w;
    }
    {
        h8 fr = s_frame8[frm3];
        float o5 = (float)s_o5h[frm3];
        float o[3];
        ppisp_px(v3.x, v3.y, v3.z, p3.x, p3.y, cam3, fr, o5, invw, invh, s_cam, o);
        F3 w; w.x = o[0]; w.y = o[1]; w.z = o[2];
        out3[i3] = w;
    }
}

// ---- 2 px/thread variant (R11, kept for n%4096!=0 but %2048==0) ----
__global__ __launch_bounds__(1024, 8)
void ppisp_px2(const float* __restrict__ rgb,
               const float* __restrict__ pc,
               const int*   __restrict__ cam_idx,
               const int*   __restrict__ frm_idx,
               const unsigned char* __restrict__ ws,
               const int*   __restrict__ resw_p,
               const int*   __restrict__ resh_p,
               float* __restrict__ out)
{
    __shared__ __align__(16) unsigned char s_tab[WS_PAD];

    int i0 = blockIdx.x * 2048 + threadIdx.x;
    int i1 = i0 + 1024;

    const int4* g = (const int4*)ws;
    int4 st0 = g[threadIdx.x];
    int4 st1 = g[threadIdx.x + 1024];

    int frm0 = frm_idx[i0];
    int frm1 = frm_idx[i1];
    int cam0 = cam_idx[i0];
    int cam1 = cam_idx[i1];
    const F3* rgb3 = (const F3*)rgb;
    const float2* pc2 = (const float2*)pc;
    F3 v0 = rgb3[i0];
    F3 v1 = rgb3[i1];
    float2 p0 = pc2[i0];
    float2 p1 = pc2[i1];
    int rw = *resw_p;
    int rh = *resh_p;

    int4* s = (int4*)s_tab;
    s[threadIdx.x] = st0;
    s[threadIdx.x + 1024] = st1;
    __syncthreads();

    const h8*       s_frame8 = (const h8*)s_tab;
    const _Float16* s_o5h    = (const _Float16*)(s_tab + WS_O5_OFF);
    const float*    s_cam    = (const float*)(s_tab + WS_CAM_OFF);

    float invw = 1.0f / (float)rw;
    float invh = 1.0f / (float)rh;

    F3* out3 = (F3*)out;

    {
        h8 fr = s_frame8[frm0];
        float o5 = (float)s_o5h[frm0];
        float o[3];
        ppisp_px(v0.x, v0.y, v0.z, p0.x, p0.y, cam0, fr, o5, invw, invh, s_cam, o);
        F3 w; w.x = o[0]; w.y = o[1]; w.z = o[2];
        out3[i0] = w;
    }
    {
        h8 fr = s_frame8[frm1];
        float o5 = (float)s_o5h[frm1];
        float o[3];
        ppisp_px(v1.x, v1.y, v1.z, p1.x, p1.y, cam1, fr, o5, invw, invh, s_cam, o);
        F3 w; w.x = o[0]; w.y = o[1]; w.z = o[2];
        out3[i1] = w;
    }
}

// ---------------- generic kernel (bounds-checked) ----------------
__global__ __launch_bounds__(256, 8)
void ppisp_main(const float* __restrict__ rgb,
                const float* __restrict__ pc,
                const int*   __restrict__ cam_idx,
                const int*   __restrict__ frm_idx,
                const unsigned char* __restrict__ ws,
                const int*   __restrict__ resw_p,
                const int*   __restrict__ resh_p,
                float* __restrict__ out,
                int n)
{
    __shared__ __align__(16) unsigned char s_tab[WS_REAL];
    {
        const int4* g = (const int4*)ws;
        int4* s = (int4*)s_tab;
#pragma unroll
        for (int i = threadIdx.x; i < WS_REAL / 16; i += 256) s[i] = g[i];
    }
    __syncthreads();

    const h8*       s_frame8 = (const h8*)s_tab;
    const _Float16* s_o5h    = (const _Float16*)(s_tab + WS_O5_OFF);
    const float*    s_cam    = (const float*)(s_tab + WS_CAM_OFF);

    float invw = 1.0f / (float)(*resw_p);
    float invh = 1.0f / (float)(*resh_p);

    const float4* rgb4 = (const float4*)rgb;
    const float4* pc4  = (const float4*)pc;
    const int4*   cam4 = (const int4*)cam_idx;
    const int4*   frm4 = (const int4*)frm_idx;
    float4* out4 = (float4*)out;

    int ngroups = n >> 2;
    int gi = blockIdx.x * 256 + threadIdx.x;

    if (gi < ngroups) {
        int4 fm = frm4[gi];
        int4 cm = cam4[gi];
        float4 r0 = rgb4[gi * 3 + 0];
        float4 r1 = rgb4[gi * 3 + 1];
        float4 r2 = rgb4[gi * 3 + 2];
        float4 p0 = pc4[gi * 2 + 0];
        float4 p1 = pc4[gi * 2 + 1];
        ppisp_group(gi, r0, r1, r2, p0, p1, cm, fm, invw, invh,
                    s_frame8, s_o5h, s_cam, out4);
    }

    int rem_start = ngroups << 2;
    int nrem = n - rem_start;
    if (blockIdx.x == 0 && (int)threadIdx.x < nrem) {
        int i = rem_start + threadIdx.x;
        int f = frm_idx[i];
        float o[3];
        ppisp_px(rgb[i * 3], rgb[i * 3 + 1], rgb[i * 3 + 2],
                 pc[i * 2], pc[i * 2 + 1],
                 cam_idx[i], s_frame8[f], (float)s_o5h[f], invw, invh, s_cam, o);
        out[i * 3 + 0] = o[0];
        out[i * 3 + 1] = o[1];
        out[i * 3 + 2] = o[2];
    }
}

// ---------------- fallback for tiny ws (in-kernel table build) ----------------
__global__ __launch_bounds__(256, 8)
void ppisp_fallback(const float* __restrict__ rgb, const float* __restrict__ pc,
                    const int* __restrict__ cam_idx, const int* __restrict__ frm_idx,
                    const float* __restrict__ expo, const float* __restrict__ vigp,
                    const float* __restrict__ cp, const float* __restrict__ crf,
                    const int* __restrict__ resw_p, const int* __restrict__ resh_p,
                    float* __restrict__ out, int n)
{
    __shared__ __align__(16) h8 s_frame8[NUM_FRAMES];
    __shared__ _Float16 s_o5h[NUM_FRAMES];
    __shared__ __align__(16) float s_cam[NUM_CAM * 3 * CROW];

    for (int f = threadIdx.x; f < NUM_FRAMES; f += blockDim.x) {
        float e = expo[f];
        const float* c = cp + f * 8;
        h8 row;
        row[0] = (_Float16)expf(e + c[0]);
        row[1] = (_Float16)expf(e);
        row[2] = (_Float16)expf(e + c[1]);
        row[3] = (_Float16)c[2]; row[4] = (_Float16)c[3];
        row[5] = (_Float16)c[4]; row[6] = (_Float16)c[5];
        row[7] = (_Float16)c[6];
        s_frame8[f] = row;
        s_o5h[f] = (_Float16)c[7];
    }
    for (int rr = threadIdx.x; rr < NUM_CAM * 3; rr += blockDim.x) {
        const float* v = vigp + rr * 5;
        const float* k = crf + rr * 4;
        float* d = s_cam + rr * CROW;
        d[0] = v[0]; d[1] = v[1]; d[2] = v[2]; d[3] = v[3];
        d[4] = v[4];
        d[5] = 0.3f + softplus_acc(k[0]);
        d[6] = 0.3f + softplus_acc(k[1]);
        d[7] = 0.1f + softplus_acc(k[2]);
        d[8] = k[3];
        d[9] = 0.f; d[10] = 0.f; d[11] = 0.f;
    }
    __syncthreads();

    float invw = 1.0f / (float)(*resw_p);
    float invh = 1.0f / (float)(*resh_p);
    const float4* rgb4 = (const float4*)rgb;
    const float4* pc4  = (const float4*)pc;
    const int4* cam4 = (const int4*)cam_idx;
    const int4* frm4 = (const int4*)frm_idx;
    float4* out4 = (float4*)out;

    int ngroups = n >> 2;
    int stride = gridDim.x * blockDim.x;
    for (int gi = blockIdx.x * blockDim.x + threadIdx.x; gi < ngroups; gi += stride) {
        int4 fm = frm4[gi];
        int4 cm = cam4[gi];
        float4 r0 = rgb4[gi * 3 + 0], r1 = rgb4[gi * 3 + 1], r2 = rgb4[gi * 3 + 2];
        float4 p0 = pc4[gi * 2 + 0], p1 = pc4[gi * 2 + 1];
        ppisp_group(gi, r0, r1, r2, p0, p1, cm, fm, invw, invh,
                    s_frame8, s_o5h, s_cam, out4);
    }
    int rem_start = ngroups << 2;
    int nrem = n - rem_start;
    if (blockIdx.x == 0 && (int)threadIdx.x < nrem) {
        int i = rem_start + threadIdx.x;
        int f = frm_idx[i];
        float o[3];
        ppisp_px(rgb[i * 3], rgb[i * 3 + 1], rgb[i * 3 + 2], pc[i * 2], pc[i * 2 + 1],
                 cam_idx[i], s_frame8[f], (float)s_o5h[f], invw, invh, s_cam, o);
        out[i * 3 + 0] = o[0]; out[i * 3 + 1] = o[1]; out[i * 3 + 2] = o[2];
    }
}

extern "C" void kernel_launch(void* const* d_in, const int* in_sizes, int n_in,
                              void* d_out, int out_size, void* d_ws, size_t ws_size,
                              hipStream_t stream)
{
    const float* rgb  = (const float*)d_in[0];
    const float* pc   = (const float*)d_in[1];
    const int*   cam  = (const int*)d_in[2];
    const int*   frm  = (const int*)d_in[3];
    const float* expo = (const float*)d_in[4];
    const float* vigp = (const float*)d_in[5];
    const float* cp   = (const float*)d_in[6];
    const float* crf  = (const float*)d_in[7];
    const int*   resw = (const int*)d_in[8];
    const int*   resh = (const int*)d_in[9];
    float* out = (float*)d_out;

    int n = in_sizes[2];   // number of pixels
    int ngroups = (n + 3) / 4;

    if (ws_size >= (size_t)WS_PAD && (n & 4095) == 0) {
        // exact path: 4 px/thread, 1024-thread blocks
        build_tables<<<dim3(4), dim3(256), 0, stream>>>(expo, cp, vigp, crf, (unsigned char*)d_ws);
        ppisp_px4<<<dim3(n / 4096), dim3(1024), 0, stream>>>(
            rgb, pc, cam, frm, (const unsigned char*)d_ws, resw, resh, out);
    } else if (ws_size >= (size_t)WS_PAD && (n & 2047) == 0) {
        build_tables<<<dim3(4), dim3(256), 0, stream>>>(expo, cp, vigp, crf, (unsigned char*)d_ws);
        ppisp_px2<<<dim3(n / 2048), dim3(1024), 0, stream>>>(
            rgb, pc, cam, frm, (const unsigned char*)d_ws, resw, resh, out);
    } else if (ws_size >= (size_t)WS_REAL) {
        build_tables<<<dim3(4), dim3(256), 0, stream>>>(expo, cp, vigp, crf, (unsigned char*)d_ws);
        int blocks = (ngroups + 255) / 256;
        ppisp_main<<<dim3(blocks), dim3(256), 0, stream>>>(
            rgb, pc, cam, frm, (const unsigned char*)d_ws, resw, resh, out, n);
    } else {
        int blocks = (ngroups + 255) / 256;
        if (blocks > 2048) blocks = 2048;
        ppisp_fallback<<<dim3(blocks), dim3(256), 0, stream>>>(
            rgb, pc, cam, frm, expo, vigp, cp, crf, resw, resh, out, n);
    }
}

// Round 13
// 64.437 us; speedup vs baseline: 1.0698x; 1.0698x over previous
//
#include <hip/hip_runtime.h>

#define NUM_FRAMES 1000
#define NUM_CAM    8
#define CROW       12   // cam channel row: {cx,cy,a2,a3, a4,k1,k2,k3, k4,pad,pad,pad}

typedef _Float16 h8 __attribute__((ext_vector_type(8)));

struct __align__(4) F3 { float x, y, z; };

#define LOG2E 1.44269504088896f
#define LN2   0.69314718055995f

// raw-builtin softplus: log1p(exp(x)); inputs are O(0.1..0.5), guard large x
__device__ __forceinline__ float softplus_fast(float x) {
    if (x > 20.0f) return x;
    float e = __builtin_amdgcn_exp2f(x * LOG2E);
    return __builtin_amdgcn_logf(1.0f + e) * LN2;
}
__device__ __forceinline__ float exp_fast(float x) {
    return __builtin_amdgcn_exp2f(x * LOG2E);
}
// CRF pow: inputs clamped >=1e-6 (no denormals) -> raw v_log_f32/v_exp_f32 safe
__device__ __forceinline__ float crf_pow(float m, float k3) {
    return __builtin_amdgcn_exp2f(k3 * __builtin_amdgcn_logf(fmaxf(m, 1e-6f)));
}

// ---------------- per-pixel math ----------------
__device__ __forceinline__ void ppisp_px(
    float r, float g, float b, float px, float py,
    int cam, h8 fr, float o5, float invw, float invh,
    const float* __restrict__ s_cam,
    float* o)
{
    float er = (float)fr[0], eg = (float)fr[1], eb = (float)fr[2];
    float o0 = (float)fr[3], o1 = (float)fr[4], o2 = (float)fr[5];
    float o3 = (float)fr[6], o4 = (float)fr[7];

    float nx = px * invw - 0.5f;
    float ny = py * invh - 0.5f;

    float xin[3] = { r * er, g * eg, b * eb };
    float xv[3];
    float k1v[3], k2v[3], k3v[3], k4v[3];
#pragma unroll
    for (int ch = 0; ch < 3; ++ch) {
        const float* c = s_cam + (cam * 3 + ch) * CROW;
        float4 c0 = *(const float4*)(c);      // cx,cy,a2,a3
        float4 c1 = *(const float4*)(c + 4);  // a4,k1,k2,k3
        float  k4 = c[8];
        float dx = nx - c0.x;
        float dy = ny - c0.y;
        float r2 = __builtin_fmaf(dx, dx, dy * dy);
        float vg = __builtin_fmaf(__builtin_fmaf(__builtin_fmaf(c1.x, r2, c0.w), r2, c0.z), r2, 1.0f);
        xv[ch] = xin[ch] * vg;
        k1v[ch] = c1.y; k2v[ch] = c1.z; k3v[ch] = c1.w; k4v[ch] = k4;
    }

    float m[3];
    m[0] = __builtin_fmaf(o0, xv[1], __builtin_fmaf(o1, xv[2], xv[0]));
    m[1] = __builtin_fmaf(o2, xv[0], __builtin_fmaf(o3, xv[2], xv[1]));
    m[2] = __builtin_fmaf(o4, xv[0], __builtin_fmaf(o5, xv[1], xv[2]));

#pragma unroll
    for (int ch = 0; ch < 3; ++ch) {
        float xg  = crf_pow(m[ch], k3v[ch]);
        float den = __builtin_fmaf(k1v[ch] - 1.0f, xg, k2v[ch]);
        o[ch] = __builtin_fmaf(k1v[ch] * xg, __builtin_amdgcn_rcpf(den), k4v[ch]);
    }
}

// ---- exact single-kernel path: 1024 threads, 4 px/thread, in-block table build ----
__global__ __launch_bounds__(1024, 8)
void ppisp_px4(const float* __restrict__ rgb,
               const float* __restrict__ pc,
               const int*   __restrict__ cam_idx,
               const int*   __restrict__ frm_idx,
               const float* __restrict__ expo,
               const float* __restrict__ cp,
               const float* __restrict__ vigp,
               const float* __restrict__ crf,
               const int*   __restrict__ resw_p,
               const int*   __restrict__ resh_p,
               float* __restrict__ out)
{
    __shared__ __align__(16) h8 s_frame8[NUM_FRAMES];          // 16 KB
    __shared__ _Float16 s_o5h[NUM_FRAMES];                     // 2 KB
    __shared__ __align__(16) float s_cam[NUM_CAM * 3 * CROW];  // 1.125 KB

    int t = threadIdx.x;
    int i0 = blockIdx.x * 4096 + t;
    int i1 = i0 + 1024;
    int i2 = i0 + 2048;
    int i3 = i0 + 3072;

    // 1) table-source loads FIRST (oldest in vmcnt order): the ds_writes
    //    below wait only on these, leaving px loads in flight.
    float e = 0.f;
    float4 ca = make_float4(0.f, 0.f, 0.f, 0.f);
    float4 cb = ca;
    if (t < NUM_FRAMES) {
        e  = expo[t];
        ca = *(const float4*)(cp + t * 8);
        cb = *(const float4*)(cp + t * 8 + 4);
    }
    float v0c = 0.f, v1c = 0.f, v2c = 0.f, v3c = 0.f, v4c = 0.f;
    float k0c = 0.f, k1c = 0.f, k2c = 0.f, k3c = 0.f;
    if (t < NUM_CAM * 3) {
        const float* v = vigp + t * 5;
        const float* k = crf + t * 4;
        v0c = v[0]; v1c = v[1]; v2c = v[2]; v3c = v[3]; v4c = v[4];
        k0c = k[0]; k1c = k[1]; k2c = k[2]; k3c = k[3];
    }

    // 2) px streaming loads (younger) — HBM latency overlaps table build + barrier
    int frm0 = frm_idx[i0], frm1 = frm_idx[i1], frm2 = frm_idx[i2], frm3 = frm_idx[i3];
    int cam0 = cam_idx[i0], cam1 = cam_idx[i1], cam2 = cam_idx[i2], cam3 = cam_idx[i3];
    const F3* rgb3 = (const F3*)rgb;
    const float2* pc2 = (const float2*)pc;
    F3 v0 = rgb3[i0], v1 = rgb3[i1], v2 = rgb3[i2], v3 = rgb3[i3];
    float2 p0 = pc2[i0], p1 = pc2[i1], p2 = pc2[i2], p3 = pc2[i3];
    int rw = *resw_p;
    int rh = *resh_p;

    // 3) build tables in-LDS (cheap now: raw v_exp/v_log builtins) + barrier
    if (t < NUM_FRAMES) {
        h8 row;
        row[0] = (_Float16)exp_fast(e + ca.x);
        row[1] = (_Float16)exp_fast(e);
        row[2] = (_Float16)exp_fast(e + ca.y);
        row[3] = (_Float16)ca.z;
        row[4] = (_Float16)ca.w;
        row[5] = (_Float16)cb.x;
        row[6] = (_Float16)cb.y;
        row[7] = (_Float16)cb.z;
        s_frame8[t] = row;
        s_o5h[t] = (_Float16)cb.w;
    }
    if (t < NUM_CAM * 3) {
        float* d = s_cam + t * CROW;
        d[0] = v0c; d[1] = v1c; d[2] = v2c; d[3] = v3c;
        d[4] = v4c;
        d[5] = 0.3f + softplus_fast(k0c);
        d[6] = 0.3f + softplus_fast(k1c);
        d[7] = 0.1f + softplus_fast(k2c);
        d[8] = k3c;
        d[9] = 0.f; d[10] = 0.f; d[11] = 0.f;
    }
    __syncthreads();

    float invw = 1.0f / (float)rw;
    float invh = 1.0f / (float)rh;

    F3* out3 = (F3*)out;

    // 4) four independent gather+compute+store sections
    {
        h8 fr = s_frame8[frm0];
        float o5 = (float)s_o5h[frm0];
        float o[3];
        ppisp_px(v0.x, v0.y, v0.z, p0.x, p0.y, cam0, fr, o5, invw, invh, s_cam, o);
        F3 w; w.x = o[0]; w.y = o[1]; w.z = o[2];
        out3[i0] = w;
    }
    {
        h8 fr = s_frame8[frm1];
        float o5 = (float)s_o5h[frm1];
        float o[3];
        ppisp_px(v1.x, v1.y, v1.z, p1.x, p1.y, cam1, fr, o5, invw, invh, s_cam, o);
        F3 w; w.x = o[0]; w.y = o[1]; w.z = o[2];
        out3[i1] = w;
    }
    {
        h8 fr = s_frame8[frm2];
        float o5 = (float)s_o5h[frm2];
        float o[3];
        ppisp_px(v2.x, v2.y, v2.z, p2.x, p2.y, cam2, fr, o5, invw, invh, s_cam, o);
        F3 w; w.x = o[0]; w.y = o[1]; w.z = o[2];
        out3[i2] = w;
    }
    {
        h8 fr = s_frame8[frm3];
        float o5 = (float)s_o5h[frm3];
        float o[3];
        ppisp_px(v3.x, v3.y, v3.z, p3.x, p3.y, cam3, fr, o5, invw, invh, s_cam, o);
        F3 w; w.x = o[0]; w.y = o[1]; w.z = o[2];
        out3[i3] = w;
    }
}

// ---------------- generic fallback (bounds-checked, in-block build) ----------------
__device__ __forceinline__ void ppisp_group(
    int gi, float4 r0, float4 r1, float4 r2, float4 p0, float4 p1,
    int4 cm, int4 fm, float invw, float invh,
    const h8* __restrict__ s_frame8, const _Float16* __restrict__ s_o5h,
    const float* __restrict__ s_cam, float4* __restrict__ out4)
{
    h8 f0 = s_frame8[fm.x];
    h8 f1 = s_frame8[fm.y];
    h8 f2 = s_frame8[fm.z];
    h8 f3 = s_frame8[fm.w];
    float o5a = (float)s_o5h[fm.x];
    float o5b = (float)s_o5h[fm.y];
    float o5c = (float)s_o5h[fm.z];
    float o5d = (float)s_o5h[fm.w];

    float a[3], bb[3], c[3], d[3];
    ppisp_px(r0.x, r0.y, r0.z, p0.x, p0.y, cm.x, f0, o5a, invw, invh, s_cam, a);
    ppisp_px(r0.w, r1.x, r1.y, p0.z, p0.w, cm.y, f1, o5b, invw, invh, s_cam, bb);
    ppisp_px(r1.z, r1.w, r2.x, p1.x, p1.y, cm.z, f2, o5c, invw, invh, s_cam, c);
    ppisp_px(r2.y, r2.z, r2.w, p1.z, p1.w, cm.w, f3, o5d, invw, invh, s_cam, d);

    out4[gi * 3 + 0] = make_float4(a[0], a[1], a[2], bb[0]);
    out4[gi * 3 + 1] = make_float4(bb[1], bb[2], c[0], c[1]);
    out4[gi * 3 + 2] = make_float4(c[2], d[0], d[1], d[2]);
}

__global__ __launch_bounds__(256, 8)
void ppisp_fallback(const float* __restrict__ rgb, const float* __restrict__ pc,
                    const int* __restrict__ cam_idx, const int* __restrict__ frm_idx,
                    const float* __restrict__ expo, const float* __restrict__ vigp,
                    const float* __restrict__ cp, const float* __restrict__ crf,
                    const int* __restrict__ resw_p, const int* __restrict__ resh_p,
                    float* __restrict__ out, int n)
{
    __shared__ __align__(16) h8 s_frame8[NUM_FRAMES];
    __shared__ _Float16 s_o5h[NUM_FRAMES];
    __shared__ __align__(16) float s_cam[NUM_CAM * 3 * CROW];

    for (int f = threadIdx.x; f < NUM_FRAMES; f += blockDim.x) {
        float e = expo[f];
        const float* c = cp + f * 8;
        h8 row;
        row[0] = (_Float16)exp_fast(e + c[0]);
        row[1] = (_Float16)exp_fast(e);
        row[2] = (_Float16)exp_fast(e + c[1]);
        row[3] = (_Float16)c[2]; row[4] = (_Float16)c[3];
        row[5] = (_Float16)c[4]; row[6] = (_Float16)c[5];
        row[7] = (_Float16)c[6];
        s_frame8[f] = row;
        s_o5h[f] = (_Float16)c[7];
    }
    for (int rr = threadIdx.x; rr < NUM_CAM * 3; rr += blockDim.x) {
        const float* v = vigp + rr * 5;
        const float* k = crf + rr * 4;
        float* d = s_cam + rr * CROW;
        d[0] = v[0]; d[1] = v[1]; d[2] = v[2]; d[3] = v[3];
        d[4] = v[4];
        d[5] = 0.3f + softplus_fast(k[0]);
        d[6] = 0.3f + softplus_fast(k[1]);
        d[7] = 0.1f + softplus_fast(k[2]);
        d[8] = k[3];
        d[9] = 0.f; d[10] = 0.f; d[11] = 0.f;
    }
    __syncthreads();

    float invw = 1.0f / (float)(*resw_p);
    float invh = 1.0f / (float)(*resh_p);
    const float4* rgb4 = (const float4*)rgb;
    const float4* pc4  = (const float4*)pc;
    const int4* cam4 = (const int4*)cam_idx;
    const int4* frm4 = (const int4*)frm_idx;
    float4* out4 = (float4*)out;

    int ngroups = n >> 2;
    int stride = gridDim.x * blockDim.x;
    for (int gi = blockIdx.x * blockDim.x + threadIdx.x; gi < ngroups; gi += stride) {
        int4 fm = frm4[gi];
        int4 cm = cam4[gi];
        float4 r0 = rgb4[gi * 3 + 0], r1 = rgb4[gi * 3 + 1], r2 = rgb4[gi * 3 + 2];
        float4 p0 = pc4[gi * 2 + 0], p1 = pc4[gi * 2 + 1];
        ppisp_group(gi, r0, r1, r2, p0, p1, cm, fm, invw, invh,
                    s_frame8, s_o5h, s_cam, out4);
    }
    int rem_start = ngroups << 2;
    int nrem = n - rem_start;
    if (blockIdx.x == 0 && (int)threadIdx.x < nrem) {
        int i = rem_start + threadIdx.x;
        int f = frm_idx[i];
        float o[3];
        ppisp_px(rgb[i * 3], rgb[i * 3 + 1], rgb[i * 3 + 2], pc[i * 2], pc[i * 2 + 1],
                 cam_idx[i], s_frame8[f], (float)s_o5h[f], invw, invh, s_cam, o);
        out[i * 3 + 0] = o[0]; out[i * 3 + 1] = o[1]; out[i * 3 + 2] = o[2];
    }
}

extern "C" void kernel_launch(void* const* d_in, const int* in_sizes, int n_in,
                              void* d_out, int out_size, void* d_ws, size_t ws_size,
                              hipStream_t stream)
{
    const float* rgb  = (const float*)d_in[0];
    const float* pc   = (const float*)d_in[1];
    const int*   cam  = (const int*)d_in[2];
    const int*   frm  = (const int*)d_in[3];
    const float* expo = (const float*)d_in[4];
    const float* vigp = (const float*)d_in[5];
    const float* cp   = (const float*)d_in[6];
    const float* crf  = (const float*)d_in[7];
    const int*   resw = (const int*)d_in[8];
    const int*   resh = (const int*)d_in[9];
    float* out = (float*)d_out;

    int n = in_sizes[2];   // number of pixels

    if ((n & 4095) == 0) {
        // exact single-kernel path: 4 px/thread, 1024-thread blocks, no ws
        ppisp_px4<<<dim3(n / 4096), dim3(1024), 0, stream>>>(
            rgb, pc, cam, frm, expo, cp, vigp, crf, resw, resh, out);
    } else {
        int ngroups = (n + 3) / 4;
        int blocks = (ngroups + 255) / 256;
        if (blocks > 2048) blocks = 2048;
        ppisp_fallback<<<dim3(blocks), dim3(256), 0, stream>>>(
            rgb, pc, cam, frm, expo, vigp, cp, crf, resw, resh, out, n);
    }
}

// Round 14
// 63.692 us; speedup vs baseline: 1.0824x; 1.0117x over previous
//
#include <hip/hip_runtime.h>

#define NUM_FRAMES 1000
#define NUM_CAM    8
#define CROW       12   // cam channel row: {cx,cy,a2,a3, a4,k1,k2,k3, k4,pad,pad,pad}

typedef _Float16 h8 __attribute__((ext_vector_type(8)));

struct __align__(4) F3 { float x, y, z; };

#define LOG2E 1.44269504088896f
#define LN2   0.69314718055995f

__device__ __forceinline__ float softplus_fast(float x) {
    if (x > 20.0f) return x;
    float e = __builtin_amdgcn_exp2f(x * LOG2E);
    return __builtin_amdgcn_logf(1.0f + e) * LN2;
}
__device__ __forceinline__ float exp_fast(float x) {
    return __builtin_amdgcn_exp2f(x * LOG2E);
}
__device__ __forceinline__ float crf_pow(float m, float k3) {
    return __builtin_amdgcn_exp2f(k3 * __builtin_amdgcn_logf(fmaxf(m, 1e-6f)));
}

// ---------------- per-pixel math ----------------
__device__ __forceinline__ void ppisp_px(
    float r, float g, float b, float px, float py,
    int cam, h8 fr, float o5, float invw, float invh,
    const float* __restrict__ s_cam,
    float* o)
{
    float er = (float)fr[0], eg = (float)fr[1], eb = (float)fr[2];
    float o0 = (float)fr[3], o1 = (float)fr[4], o2 = (float)fr[5];
    float o3 = (float)fr[6], o4 = (float)fr[7];

    float nx = px * invw - 0.5f;
    float ny = py * invh - 0.5f;

    float xin[3] = { r * er, g * eg, b * eb };
    float xv[3];
    float k1v[3], k2v[3], k3v[3], k4v[3];
#pragma unroll
    for (int ch = 0; ch < 3; ++ch) {
        const float* c = s_cam + (cam * 3 + ch) * CROW;
        float4 c0 = *(const float4*)(c);      // cx,cy,a2,a3
        float4 c1 = *(const float4*)(c + 4);  // a4,k1,k2,k3
        float  k4 = c[8];
        float dx = nx - c0.x;
        float dy = ny - c0.y;
        float r2 = __builtin_fmaf(dx, dx, dy * dy);
        float vg = __builtin_fmaf(__builtin_fmaf(__builtin_fmaf(c1.x, r2, c0.w), r2, c0.z), r2, 1.0f);
        xv[ch] = xin[ch] * vg;
        k1v[ch] = c1.y; k2v[ch] = c1.z; k3v[ch] = c1.w; k4v[ch] = k4;
    }

    float m[3];
    m[0] = __builtin_fmaf(o0, xv[1], __builtin_fmaf(o1, xv[2], xv[0]));
    m[1] = __builtin_fmaf(o2, xv[0], __builtin_fmaf(o3, xv[2], xv[1]));
    m[2] = __builtin_fmaf(o4, xv[0], __builtin_fmaf(o5, xv[1], xv[2]));

#pragma unroll
    for (int ch = 0; ch < 3; ++ch) {
        float xg  = crf_pow(m[ch], k3v[ch]);
        float den = __builtin_fmaf(k1v[ch] - 1.0f, xg, k2v[ch]);
        o[ch] = __builtin_fmaf(k1v[ch] * xg, __builtin_amdgcn_rcpf(den), k4v[ch]);
    }
}

// ---- exact path: 512 threads, 4 px/thread, in-block build, 4 blocks/CU ----
__global__ __launch_bounds__(512, 8)
void ppisp_px4(const float* __restrict__ rgb,
               const float* __restrict__ pc,
               const int*   __restrict__ cam_idx,
               const int*   __restrict__ frm_idx,
               const float* __restrict__ expo,
               const float* __restrict__ cp,
               const float* __restrict__ vigp,
               const float* __restrict__ crf,
               const int*   __restrict__ resw_p,
               const int*   __restrict__ resh_p,
               float* __restrict__ out)
{
    __shared__ __align__(16) h8 s_frame8[NUM_FRAMES];          // 16 KB
    __shared__ _Float16 s_o5h[NUM_FRAMES];                     // 2 KB
    __shared__ __align__(16) float s_cam[NUM_CAM * 3 * CROW];  // 1.125 KB

    int t = threadIdx.x;
    int i0 = blockIdx.x * 2048 + t;
    int i1 = i0 + 512;
    int i2 = i0 + 1024;
    int i3 = i0 + 1536;

    // 1) table-source loads FIRST (oldest in vmcnt order): ds_writes below
    //    wait only on these, leaving the px loads in flight. 2 rows/thread.
    int f0i = t;            // < 512
    int f1i = t + 512;      // < 1024; valid if < 1000
    float e0 = expo[f0i];
    float4 ca0 = *(const float4*)(cp + f0i * 8);
    float4 cb0 = *(const float4*)(cp + f0i * 8 + 4);
    float e1 = 0.f;
    float4 ca1 = make_float4(0.f, 0.f, 0.f, 0.f);
    float4 cb1 = ca1;
    if (f1i < NUM_FRAMES) {
        e1  = expo[f1i];
        ca1 = *(const float4*)(cp + f1i * 8);
        cb1 = *(const float4*)(cp + f1i * 8 + 4);
    }
    float v0c = 0.f, v1c = 0.f, v2c = 0.f, v3c = 0.f, v4c = 0.f;
    float k0c = 0.f, k1c = 0.f, k2c = 0.f, k3c = 0.f;
    if (t < NUM_CAM * 3) {
        const float* v = vigp + t * 5;
        const float* k = crf + t * 4;
        v0c = v[0]; v1c = v[1]; v2c = v[2]; v3c = v[3]; v4c = v[4];
        k0c = k[0]; k1c = k[1]; k2c = k[2]; k3c = k[3];
    }

    // 2) px streaming loads (younger) — HBM latency overlaps build + barrier
    int frm0 = frm_idx[i0], frm1 = frm_idx[i1], frm2 = frm_idx[i2], frm3 = frm_idx[i3];
    int cam0 = cam_idx[i0], cam1 = cam_idx[i1], cam2 = cam_idx[i2], cam3 = cam_idx[i3];
    const F3* rgb3 = (const F3*)rgb;
    const float2* pc2 = (const float2*)pc;
    F3 v0 = rgb3[i0], v1 = rgb3[i1], v2 = rgb3[i2], v3 = rgb3[i3];
    float2 p0 = pc2[i0], p1 = pc2[i1], p2 = pc2[i2], p3 = pc2[i3];
    int rw = *resw_p;
    int rh = *resh_p;

    // 3) build tables in-LDS + barrier
    {
        h8 row;
        row[0] = (_Float16)exp_fast(e0 + ca0.x);
        row[1] = (_Float16)exp_fast(e0);
        row[2] = (_Float16)exp_fast(e0 + ca0.y);
        row[3] = (_Float16)ca0.z;
        row[4] = (_Float16)ca0.w;
        row[5] = (_Float16)cb0.x;
        row[6] = (_Float16)cb0.y;
        row[7] = (_Float16)cb0.z;
        s_frame8[f0i] = row;
        s_o5h[f0i] = (_Float16)cb0.w;
    }
    if (f1i < NUM_FRAMES) {
        h8 row;
        row[0] = (_Float16)exp_fast(e1 + ca1.x);
        row[1] = (_Float16)exp_fast(e1);
        row[2] = (_Float16)exp_fast(e1 + ca1.y);
        row[3] = (_Float16)ca1.z;
        row[4] = (_Float16)ca1.w;
        row[5] = (_Float16)cb1.x;
        row[6] = (_Float16)cb1.y;
        row[7] = (_Float16)cb1.z;
        s_frame8[f1i] = row;
        s_o5h[f1i] = (_Float16)cb1.w;
    }
    if (t < NUM_CAM * 3) {
        float* d = s_cam + t * CROW;
        d[0] = v0c; d[1] = v1c; d[2] = v2c; d[3] = v3c;
        d[4] = v4c;
        d[5] = 0.3f + softplus_fast(k0c);
        d[6] = 0.3f + softplus_fast(k1c);
        d[7] = 0.1f + softplus_fast(k2c);
        d[8] = k3c;
        d[9] = 0.f; d[10] = 0.f; d[11] = 0.f;
    }
    __syncthreads();

    float invw = 1.0f / (float)rw;
    float invh = 1.0f / (float)rh;

    F3* out3 = (F3*)out;

    // 4) four independent gather+compute+store sections
    {
        h8 fr = s_frame8[frm0];
        float o5 = (float)s_o5h[frm0];
        float o[3];
        ppisp_px(v0.x, v0.y, v0.z, p0.x, p0.y, cam0, fr, o5, invw, invh, s_cam, o);
        F3 w; w.x = o[0]; w.y = o[1]; w.z = o[2];
        out3[i0] = w;
    }
    {
        h8 fr = s_frame8[frm1];
        float o5 = (float)s_o5h[frm1];
        float o[3];
        ppisp_px(v1.x, v1.y, v1.z, p1.x, p1.y, cam1, fr, o5, invw, invh, s_cam, o);
        F3 w; w.x = o[0]; w.y = o[1]; w.z = o[2];
        out3[i1] = w;
    }
    {
        h8 fr = s_frame8[frm2];
        float o5 = (float)s_o5h[frm2];
        float o[3];
        ppisp_px(v2.x, v2.y, v2.z, p2.x, p2.y, cam2, fr, o5, invw, invh, s_cam, o);
        F3 w; w.x = o[0]; w.y = o[1]; w.z = o[2];
        out3[i2] = w;
    }
    {
        h8 fr = s_frame8[frm3];
        float o5 = (float)s_o5h[frm3];
        float o[3];
        ppisp_px(v3.x, v3.y, v3.z, p3.x, p3.y, cam3, fr, o5, invw, invh, s_cam, o);
        F3 w; w.x = o[0]; w.y = o[1]; w.z = o[2];
        out3[i3] = w;
    }
}

// ---------------- generic fallback (bounds-checked, in-block build) ----------------
__device__ __forceinline__ void ppisp_group(
    int gi, float4 r0, float4 r1, float4 r2, float4 p0, float4 p1,
    int4 cm, int4 fm, float invw, float invh,
    const h8* __restrict__ s_frame8, const _Float16* __restrict__ s_o5h,
    const float* __restrict__ s_cam, float4* __restrict__ out4)
{
    h8 f0 = s_frame8[fm.x];
    h8 f1 = s_frame8[fm.y];
    h8 f2 = s_frame8[fm.z];
    h8 f3 = s_frame8[fm.w];
    float o5a = (float)s_o5h[fm.x];
    float o5b = (float)s_o5h[fm.y];
    float o5c = (float)s_o5h[fm.z];
    float o5d = (float)s_o5h[fm.w];

    float a[3], bb[3], c[3], d[3];
    ppisp_px(r0.x, r0.y, r0.z, p0.x, p0.y, cm.x, f0, o5a, invw, invh, s_cam, a);
    ppisp_px(r0.w, r1.x, r1.y, p0.z, p0.w, cm.y, f1, o5b, invw, invh, s_cam, bb);
    ppisp_px(r1.z, r1.w, r2.x, p1.x, p1.y, cm.z, f2, o5c, invw, invh, s_cam, c);
    ppisp_px(r2.y, r2.z, r2.w, p1.z, p1.w, cm.w, f3, o5d, invw, invh, s_cam, d);

    out4[gi * 3 + 0] = make_float4(a[0], a[1], a[2], bb[0]);
    out4[gi * 3 + 1] = make_float4(bb[1], bb[2], c[0], c[1]);
    out4[gi * 3 + 2] = make_float4(c[2], d[0], d[1], d[2]);
}

__global__ __launch_bounds__(256, 8)
void ppisp_fallback(const float* __restrict__ rgb, const float* __restrict__ pc,
                    const int* __restrict__ cam_idx, const int* __restrict__ frm_idx,
                    const float* __restrict__ expo, const float* __restrict__ vigp,
                    const float* __restrict__ cp, const float* __restrict__ crf,
                    const int* __restrict__ resw_p, const int* __restrict__ resh_p,
                    float* __restrict__ out, int n)
{
    __shared__ __align__(16) h8 s_frame8[NUM_FRAMES];
    __shared__ _Float16 s_o5h[NUM_FRAMES];
    __shared__ __align__(16) float s_cam[NUM_CAM * 3 * CROW];

    for (int f = threadIdx.x; f < NUM_FRAMES; f += blockDim.x) {
        float e = expo[f];
        const float* c = cp + f * 8;
        h8 row;
        row[0] = (_Float16)exp_fast(e + c[0]);
        row[1] = (_Float16)exp_fast(e);
        row[2] = (_Float16)exp_fast(e + c[1]);
        row[3] = (_Float16)c[2]; row[4] = (_Float16)c[3];
        row[5] = (_Float16)c[4]; row[6] = (_Float16)c[5];
        row[7] = (_Float16)c[6];
        s_frame8[f] = row;
        s_o5h[f] = (_Float16)c[7];
    }
    for (int rr = threadIdx.x; rr < NUM_CAM * 3; rr += blockDim.x) {
        const float* v = vigp + rr * 5;
        const float* k = crf + rr * 4;
        float* d = s_cam + rr * CROW;
        d[0] = v[0]; d[1] = v[1]; d[2] = v[2]; d[3] = v[3];
        d[4] = v[4];
        d[5] = 0.3f + softplus_fast(k[0]);
        d[6] = 0.3f + softplus_fast(k[1]);
        d[7] = 0.1f + softplus_fast(k[2]);
        d[8] = k[3];
        d[9] = 0.f; d[10] = 0.f; d[11] = 0.f;
    }
    __syncthreads();

    float invw = 1.0f / (float)(*resw_p);
    float invh = 1.0f / (float)(*resh_p);
    const float4* rgb4 = (const float4*)rgb;
    const float4* pc4  = (const float4*)pc;
    const int4* cam4 = (const int4*)cam_idx;
    const int4* frm4 = (const int4*)frm_idx;
    float4* out4 = (float4*)out;

    int ngroups = n >> 2;
    int stride = gridDim.x * blockDim.x;
    for (int gi = blockIdx.x * blockDim.x + threadIdx.x; gi < ngroups; gi += stride) {
        int4 fm = frm4[gi];
        int4 cm = cam4[gi];
        float4 r0 = rgb4[gi * 3 + 0], r1 = rgb4[gi * 3 + 1], r2 = rgb4[gi * 3 + 2];
        float4 p0 = pc4[gi * 2 + 0], p1 = pc4[gi * 2 + 1];
        ppisp_group(gi, r0, r1, r2, p0, p1, cm, fm, invw, invh,
                    s_frame8, s_o5h, s_cam, out4);
    }
    int rem_start = ngroups << 2;
    int nrem = n - rem_start;
    if (blockIdx.x == 0 && (int)threadIdx.x < nrem) {
        int i = rem_start + threadIdx.x;
        int f = frm_idx[i];
        float o[3];
        ppisp_px(rgb[i * 3], rgb[i * 3 + 1], rgb[i * 3 + 2], pc[i * 2], pc[i * 2 + 1],
                 cam_idx[i], s_frame8[f], (float)s_o5h[f], invw, invh, s_cam, o);
        out[i * 3 + 0] = o[0]; out[i * 3 + 1] = o[1]; out[i * 3 + 2] = o[2];
    }
}

extern "C" void kernel_launch(void* const* d_in, const int* in_sizes, int n_in,
                              void* d_out, int out_size, void* d_ws, size_t ws_size,
                              hipStream_t stream)
{
    const float* rgb  = (const float*)d_in[0];
    const float* pc   = (const float*)d_in[1];
    const int*   cam  = (const int*)d_in[2];
    const int*   frm  = (const int*)d_in[3];
    const float* expo = (const float*)d_in[4];
    const float* vigp = (const float*)d_in[5];
    const float* cp   = (const float*)d_in[6];
    const float* crf  = (const float*)d_in[7];
    const int*   resw = (const int*)d_in[8];
    const int*   resh = (const int*)d_in[9];
    float* out = (float*)d_out;

    int n = in_sizes[2];   // number of pixels

    if ((n & 2047) == 0) {
        // exact path: 4 px/thread, 512-thread blocks, 4 blocks/CU
        ppisp_px4<<<dim3(n / 2048), dim3(512), 0, stream>>>(
            rgb, pc, cam, frm, expo, cp, vigp, crf, resw, resh, out);
    } else {
        int ngroups = (n + 3) / 4;
        int blocks = (ngroups + 255) / 256;
        if (blocks > 2048) blocks = 2048;
        ppisp_fallback<<<dim3(blocks), dim3(256), 0, stream>>>(
            rgb, pc, cam, frm, expo, vigp, cp, crf, resw, resh, out, n);
    }
}